// Round 5
// baseline (39726.361 us; speedup 1.0000x reference)
//
#include <hip/hip_runtime.h>
#include <hip/hip_bf16.h>

typedef __attribute__((ext_vector_type(8))) short bf16x8;
typedef __attribute__((ext_vector_type(4))) float f32x4;
typedef __attribute__((ext_vector_type(4))) float fvec4;
typedef __attribute__((ext_vector_type(4))) unsigned short u16x4;

#define DEVI __device__ __forceinline__

constexpr int BB = 256, TT = 1024, FF = 128, HH = 512, OO = 64;
constexpr int KK = 256;    // fused input width [x_imp | m]
constexpr int NN = 2048;   // fused gate width  [z | r | htilde | gamma_h]

DEVI unsigned short f2bf(float x) {
  unsigned int u = __float_as_uint(x);
  u += 0x7FFFu + ((u >> 16) & 1u);          // RNE
  return (unsigned short)(u >> 16);
}
DEVI float bf2f(unsigned short s) {
  return __uint_as_float(((unsigned int)s) << 16);
}

// async global->LDS, 16B per lane; LDS dest = uniform base + lane*16
DEVI void gload16(const unsigned short* g, unsigned short* lds) {
  __builtin_amdgcn_global_load_lds(
      (const __attribute__((address_space(1))) void*)g,
      (__attribute__((address_space(3))) void*)lds, 16, 0, 0);
}

DEVI void barrier_lds() {       // raw barrier: waits LDS ops only, vmcnt SURVIVES
  asm volatile("s_waitcnt lgkmcnt(0)" ::: "memory");
  __builtin_amdgcn_s_barrier();
  __builtin_amdgcn_sched_barrier(0);
}

// slabHG address swizzle (shorts): involution within a row, applied on BOTH
// the stage source and every read/write (rule: both-sides-or-neither).
DEVI int hgIdx(int row, int c) { return row*1024 + (c ^ ((row & 7) << 3)); }

// ---------------------------------------------------------------------------
// K0: pack weights.
//   BwT [2048][256] bf16 : row n = column n of fused K x N weight.
//   bias[2048] f32 : b_* + colsum(V_*)  (gamma rows: b_gamma_h)
//   UzrP [16 kt][64 nt][64 l][8] bf16 : nt<32 -> U_z cols, nt>=32 -> U_r cols
//   UhP  [16 kt][32 nt][64 l][8] bf16 : U
//   frag value (kt,nt,l,j) = U[kt*32 + (l>>4)*8 + j][(nt&31)*16 + (l&15)]
// ---------------------------------------------------------------------------
__global__ __launch_bounds__(256) void prep_kernel(
    const float* __restrict__ W_z, const float* __restrict__ V_z, const float* __restrict__ b_z,
    const float* __restrict__ W_r, const float* __restrict__ V_r, const float* __restrict__ b_r,
    const float* __restrict__ Wh,  const float* __restrict__ Vh,  const float* __restrict__ bh,
    const float* __restrict__ Wgh, const float* __restrict__ bgh,
    const float* __restrict__ U_z, const float* __restrict__ U_r, const float* __restrict__ Uh,
    unsigned short* __restrict__ BwT, float* __restrict__ bias,
    unsigned short* __restrict__ UzrP, unsigned short* __restrict__ UhP)
{
  int idx = blockIdx.x * 256 + threadIdx.x;
  if (idx < 524288) {                       // BwT
    int n = idx >> 8, k = idx & 255;
    float v;
    if (n < 512)       { int h = n;        v = (k < 128) ? W_z[k*HH + h] : -V_z[(k-128)*HH + h]; }
    else if (n < 1024) { int h = n - 512;  v = (k < 128) ? W_r[k*HH + h] : -V_r[(k-128)*HH + h]; }
    else if (n < 1536) { int h = n - 1024; v = (k < 128) ? Wh [k*HH + h] : -Vh [(k-128)*HH + h]; }
    else               { int h = n - 1536; v = (k < 128) ? 0.f : Wgh[(k-128)*HH + h]; }
    BwT[n*256 + k] = f2bf(v);
    return;
  }
  idx -= 524288;
  if (idx < 2048) {                         // bias
    int n = idx; float v;
    if (n < 512)       { float s = b_z[n];      for (int f = 0; f < FF; ++f) s += V_z[f*HH + n];        v = s; }
    else if (n < 1024) { int h = n-512;  float s = b_r[h]; for (int f = 0; f < FF; ++f) s += V_r[f*HH + h]; v = s; }
    else if (n < 1536) { int h = n-1024; float s = bh[h];  for (int f = 0; f < FF; ++f) s += Vh[f*HH + h];  v = s; }
    else               { v = bgh[n-1536]; }
    bias[n] = v;
    return;
  }
  idx -= 2048;
  if (idx < 524288) {                       // UzrP pack (kt-major)
    int j = idx & 7, l = (idx >> 3) & 63, nt = (idx >> 9) & 63, kt = idx >> 15;
    int k = kt*32 + (l >> 4)*8 + j;
    int col = (nt & 31)*16 + (l & 15);
    float v = (nt < 32) ? U_z[k*HH + col] : U_r[k*HH + col];
    UzrP[idx] = f2bf(v);
    return;
  }
  idx -= 524288;
  if (idx < 262144) {                       // UhP pack (kt-major)
    int j = idx & 7, l = (idx >> 3) & 63, nt = (idx >> 9) & 31, kt = idx >> 14;
    int k = kt*32 + (l >> 4)*8 + j;
    UhP[idx] = f2bf(Uh[k*HH + nt*16 + (l & 15)]);
  }
}

// ---------------------------------------------------------------------------
// K1: imputation + fused A chunk [B*TC][256] bf16 = [x_imp | m]
// ---------------------------------------------------------------------------
__global__ __launch_bounds__(256) void build_A_kernel(
    const float* __restrict__ x, const float* __restrict__ delta,
    const float* __restrict__ mm, const float* __restrict__ xf,
    const float* __restrict__ Wgx, const float* __restrict__ bgx,
    const int* __restrict__ bs, unsigned short* __restrict__ A,
    int t0, int TC)
{
  int blk = blockIdx.x;
  int row8 = blk * 8;
  int b0  = row8 / TC;
  int tl0 = row8 % TC;
  if (b0 >= bs[t0 + tl0]) return;
  int tid = threadIdx.x;
  int rl = row8 + (tid >> 5);
  int tc = tl0 + (tid >> 5);
  long gi = ((long)b0*TT + t0 + tc) * 32 + (tid & 31);
  int f0 = (tid & 31) * 4;
  fvec4 xv = ((const fvec4*)x)[gi];
  fvec4 dv = ((const fvec4*)delta)[gi];
  fvec4 mv = ((const fvec4*)mm)[gi];
  fvec4 fv = ((const fvec4*)xf)[gi];
  unsigned short ox[4], om[4];
#pragma unroll
  for (int j = 0; j < 4; ++j) {
    float g  = __expf(-fmaxf(dv[j]*Wgx[f0+j] + bgx[f0+j], 0.f));
    float xr = g*fv[j] + (1.f - g)*0.001f;
    float xi = (mv[j] > 0.5f) ? xr : xv[j];
    ox[j] = f2bf(xi); om[j] = f2bf(mv[j]);
  }
  *(u16x4*)(A + (long)rl*KK + f0)       = (u16x4){ox[0], ox[1], ox[2], ox[3]};
  *(u16x4*)(A + (long)rl*KK + 128 + f0) = (u16x4){om[0], om[1], om[2], om[3]};
}

// ---------------------------------------------------------------------------
// K2: chunk GEMM  PRE[m][n] = A[m][:] @ Bw[:,n] + bias[n]  (bf16 MFMA, K=256)
// ---------------------------------------------------------------------------
__global__ __launch_bounds__(256) void gemm1_kernel(
    const unsigned short* __restrict__ A, const unsigned short* __restrict__ BwT,
    const float* __restrict__ bias, const int* __restrict__ bs,
    unsigned short* __restrict__ PRE, int t0, int TC)
{
  int blk = blockIdx.x;
  int nt = blk & 15;
  int mt = blk >> 4;
  {
    int m0 = mt * 128;
    int b_ = m0 / TC;
    int bcheck = (TC >= 128) ? bs[t0 + (m0 % TC)] : bs[t0];
    if (b_ >= bcheck) return;
  }
  int tid = threadIdx.x;
  int w = tid >> 6, l = tid & 63;
  int wm = w >> 1, wn = w & 1;
  int lr = l & 15, lg = l >> 4;
  int m_base = mt*128 + wm*64;
  int n_base = nt*128 + wn*64;
  const unsigned short* Aptr = A   + (long)(m_base + lr)*KK + lg*8;
  const unsigned short* Bptr = BwT + (long)(n_base + lr)*KK + lg*8;
  f32x4 acc[4][4];
#pragma unroll
  for (int i = 0; i < 4; ++i)
#pragma unroll
    for (int j = 0; j < 4; ++j) acc[i][j] = (f32x4){0.f, 0.f, 0.f, 0.f};

#pragma unroll
  for (int kt = 0; kt < 8; ++kt) {
    bf16x8 af[4], bfr[4];
#pragma unroll
    for (int i = 0; i < 4; ++i) af[i]  = *(const bf16x8*)(Aptr + (long)i*16*KK + kt*32);
#pragma unroll
    for (int i = 0; i < 4; ++i) bfr[i] = *(const bf16x8*)(Bptr + (long)i*16*KK + kt*32);
#pragma unroll
    for (int ms = 0; ms < 4; ++ms)
#pragma unroll
      for (int ns = 0; ns < 4; ++ns)
        acc[ms][ns] = __builtin_amdgcn_mfma_f32_16x16x32_bf16(af[ms], bfr[ns], acc[ms][ns], 0, 0, 0);
  }
#pragma unroll
  for (int ms = 0; ms < 4; ++ms) {
    int gm0 = m_base + ms*16 + lg*4;
#pragma unroll
    for (int ns = 0; ns < 4; ++ns) {
      int gn = n_base + ns*16 + lr;
      float bv = bias[gn];
      bool is_gamma = (gn >= 1536);
#pragma unroll
      for (int q = 0; q < 4; ++q) {
        float v = acc[ms][ns][q] + bv;
        if (is_gamma) v = __expf(-fmaxf(v, 0.f));
        PRE[(long)(gm0 + q)*NN + gn] = f2bf(v);
      }
    }
  }
}

// ---------------------------------------------------------------------------
// K3: sequential scan, 16 independent blocks x 512 threads (8 waves).
//   Block owns 16 batch rows. ALL steady-state global reads go through
//   global_load_lds with statically-counted vmcnt (no VGPR loads in the loop
//   except one pz/pr clump issued AFTER all stages -> FIFO-safe):
//     S1: vmcnt(8)  -> HG slab (this step's htilde/gamma) landed; A0,A1 fly
//     per unit: vmcnt(4) -> unit u landed (depth-2 per-wave private dbuf)
//     tails: A30->B0, A31->B1; B14->HG(t+1), B15->A0(t+1), post->A1(t+1)
//   Cross-wave handoffs use raw s_barrier + lgkmcnt(0) only (vmcnt survives).
// ---------------------------------------------------------------------------
__global__ __launch_bounds__(512) void scan_kernel(
    const unsigned short* __restrict__ PRE,
    const unsigned short* __restrict__ UzrP,
    const unsigned short* __restrict__ UhP,
    const int* __restrict__ bs,
    float* __restrict__ h_st,
    int t0, int TC)
{
  __shared__ __align__(16) unsigned short Ubuf[8][2][2048];  // 64 KB per-wave dbuf
  __shared__ __align__(16) unsigned short hd_l[8192];        // 16 KB hd / hd*r frags
  __shared__ __align__(16) unsigned short slabHG[16*1024];   // 32 KB [row][htilde|r : gamma] swizzled
  __shared__ float hm[16][524];                              // 32.75 KB h master

  const int tid = threadIdx.x;
  const int r0 = blockIdx.x * 16;
  if (t0 > 0 && bs[t0] <= r0) return;

  const int w = tid >> 6, l = tid & 63, lr = l & 15, lg = l >> 4;
  const size_t rowStr = (size_t)TC * NN;     // PRE row stride (shorts)

  unsigned short* slot0 = &Ubuf[w][0][0];
  unsigned short* slot1 = &Ubuf[w][1][0];

  auto STAGEA = [&](int u) {
    const unsigned short* src = UzrP + ((size_t)((u>>1)*64 + (u&1)*32 + w*4))*512 + l*8;
    unsigned short* dst = (u & 1) ? slot1 : slot0;
#pragma unroll
    for (int i = 0; i < 4; ++i) gload16(src + i*512, dst + i*512);
  };
  auto STAGEB = [&](int u) {
    const unsigned short* src = UhP + ((size_t)(u*32 + w*4))*512 + l*8;
    unsigned short* dst = (u & 1) ? slot1 : slot0;
#pragma unroll
    for (int i = 0; i < 4; ++i) gload16(src + i*512, dst + i*512);
  };
  // stage htilde+gamma halves of PRE rows (cols 1024..2047) for a step,
  // with the hgIdx swizzle pre-applied to the per-lane global source.
  auto STAGEHG = [&](const unsigned short* PREn) {
#pragma unroll
    for (int j = 0; j < 4; ++j) {
      int idx = w*4 + j;                 // 32 half-rows over 8 waves
      int row = idx >> 1;
      int phys = (idx & 1)*512 + l*8;    // within-row short offset (linear LDS)
      int logi = phys ^ ((row & 7) << 3);
      const unsigned short* src = PREn + (size_t)row*rowStr + 1024 + logi;
      gload16(src, &slabHG[idx*512]);
    }
  };

  // load h master (VGPR loads + LDS stores, fully consumed BEFORE any stage)
  if (t0 == 0) {
    for (int i = tid; i < 16*512; i += 512) hm[i>>9][i&511] = 0.f;
  } else {
    for (int i = tid; i < 16*512; i += 512)
      hm[i>>9][i&511] = h_st[(size_t)(r0 + (i>>9))*HH + (i&511)];
  }
  __builtin_amdgcn_sched_barrier(0);

  // prologue staging: HG(t=0 of this chunk), A0, A1   (12 loads outstanding)
  STAGEHG(PRE + (size_t)r0*TC*NN);
  STAGEA(0); STAGEA(1);

  for (int tc = 0; tc < TC; ++tc) {
    const int bsv = bs[t0 + tc];
    if (bsv <= r0) break;                  // descending bs: done forever
    const int na = min(16, bsv - r0);
    const unsigned short* PREstep = PRE + ((size_t)r0*TC + tc)*NN;
    const unsigned short* PREnext = PREstep + NN;   // in-bounds even at tc=TC-1

    barrier_lds();                         // S1: prev hm writes visible
    asm volatile("s_waitcnt vmcnt(8)" ::: "memory");  // HG landed; A0,A1 fly
    __builtin_amdgcn_sched_barrier(0);

    // pz/pr clump: the ONLY VGPR global loads, issued after all stages
    unsigned short pzr[2][4][4];
#pragma unroll
    for (int i = 0; i < 4; ++i)
#pragma unroll
      for (int q = 0; q < 4; ++q) {
        int row = lg*4 + q, col = (w*4 + i)*16 + lr;
        const unsigned short* pb = PREstep + (size_t)row*rowStr + col;
        pzr[0][i][q] = pb[0];
        pzr[1][i][q] = pb[512];
      }
    __builtin_amdgcn_sched_barrier(0);

    // hd build: frag layout, gamma from slabHG
#pragma unroll
    for (int s2 = 0; s2 < 2; ++s2) {
      int s = tid + s2*512;
      int kt = s >> 6, ll = s & 63;
      int row = ll & 15, k0 = kt*32 + (ll >> 4)*8;
      bf16x8 gv = *(const bf16x8*)&slabHG[hgIdx(row, 512 + k0)];
      bool act = row < na;
      unsigned short hv[8];
#pragma unroll
      for (int j = 0; j < 8; ++j) {
        float h = hm[row][k0 + j];
        hv[j] = f2bf(act ? bf2f((unsigned short)gv[j]) * h : h);
      }
      *(u16x4*)&hd_l[s*8]     = (u16x4){hv[0], hv[1], hv[2], hv[3]};
      *(u16x4*)&hd_l[s*8 + 4] = (u16x4){hv[4], hv[5], hv[6], hv[7]};
    }

    // hoist htilde-preact + gamma for my output cells into registers
    float phv[4][4], ggv[4][4];
#pragma unroll
    for (int i = 0; i < 4; ++i)
#pragma unroll
      for (int q = 0; q < 4; ++q) {
        int row = lg*4 + q, col = (w*4 + i)*16 + lr;
        phv[i][q] = bf2f(slabHG[hgIdx(row, col)]);
        ggv[i][q] = bf2f(slabHG[hgIdx(row, 512 + col)]);
      }
    barrier_lds();                         // S2: hd_l ready

    // ---- phase A: z|r, units 0..31, per-wave private depth-2 pipeline ----
    f32x4 acc[8];
#pragma unroll
    for (int i = 0; i < 8; ++i) acc[i] = (f32x4){0.f, 0.f, 0.f, 0.f};
    bf16x8 af;
#pragma unroll
    for (int u = 0; u < 32; ++u) {
      asm volatile("s_waitcnt vmcnt(4)" ::: "memory");
      __builtin_amdgcn_sched_barrier(0);
      const unsigned short* buf = (u & 1) ? slot1 : slot0;
      if (!(u & 1)) af = *(const bf16x8*)&hd_l[((u>>1)*64 + l)*8];
#pragma unroll
      for (int i = 0; i < 4; ++i) {
        bf16x8 bf = *(const bf16x8*)&buf[i*512 + l*8];
        acc[(u&1)*4 + i] = __builtin_amdgcn_mfma_f32_16x16x32_bf16(af, bf, acc[(u&1)*4 + i], 0, 0, 0);
      }
      __builtin_amdgcn_sched_barrier(0);
      if (u < 30)       STAGEA(u + 2);
      else if (u == 30) STAGEB(0);
      else              STAGEB(1);
    }

    // epilogue A: z -> regs (same wave/lane owns col in phase B); r -> slabHG
    float zreg[4][4];
#pragma unroll
    for (int i = 0; i < 4; ++i)
#pragma unroll
      for (int q = 0; q < 4; ++q) {
        int row = lg*4 + q, col = (w*4 + i)*16 + lr;
        float pz = bf2f(pzr[0][i][q]);
        float pr = bf2f(pzr[1][i][q]);
        zreg[i][q] = 1.f/(1.f + __expf(-(pz + acc[i][q])));
        slabHG[hgIdx(row, col)] = f2bf(1.f/(1.f + __expf(-(pr + acc[4+i][q]))));
      }
    barrier_lds();                         // S3: r complete, phase-A hd_l reads done

    // a2 = hd * r, in place (same-thread same-slot)
#pragma unroll
    for (int s2 = 0; s2 < 2; ++s2) {
      int s = tid + s2*512;
      int kt = s >> 6, ll = s & 63;
      int row = ll & 15, k0 = kt*32 + (ll >> 4)*8;
      bf16x8 rv = *(const bf16x8*)&slabHG[hgIdx(row, k0)];
#pragma unroll
      for (int j = 0; j < 8; ++j)
        hd_l[s*8 + j] = f2bf(bf2f(hd_l[s*8 + j]) * bf2f((unsigned short)rv[j]));
    }
    barrier_lds();                         // S4: a2 frags ready

    // ---- phase B: htilde, units 0..15; tail stages HG(t+1), A0, A1 ----
    f32x4 accB[4];
#pragma unroll
    for (int i = 0; i < 4; ++i) accB[i] = (f32x4){0.f, 0.f, 0.f, 0.f};
#pragma unroll
    for (int u = 0; u < 16; ++u) {
      asm volatile("s_waitcnt vmcnt(4)" ::: "memory");
      __builtin_amdgcn_sched_barrier(0);
      const unsigned short* buf = (u & 1) ? slot1 : slot0;
      bf16x8 af2 = *(const bf16x8*)&hd_l[(u*64 + l)*8];
#pragma unroll
      for (int i = 0; i < 4; ++i) {
        bf16x8 bf = *(const bf16x8*)&buf[i*512 + l*8];
        accB[i] = __builtin_amdgcn_mfma_f32_16x16x32_bf16(af2, bf, accB[i], 0, 0, 0);
      }
      __builtin_amdgcn_sched_barrier(0);
      if (u < 14)       STAGEB(u + 2);
      else if (u == 14) STAGEHG(PREnext);
      else              STAGEA(0);
    }
    STAGEA(1);

    // epilogue B: h update (registers + hm only)
#pragma unroll
    for (int i = 0; i < 4; ++i)
#pragma unroll
      for (int q = 0; q < 4; ++q) {
        int row = lg*4 + q;
        if (row < na) {
          int col = (w*4 + i)*16 + lr;
          float e  = __expf(2.f*(phv[i][q] + accB[i][q]));
          float th = 1.f - 2.f/(e + 1.f);          // tanh, overflow-safe
          float hd = ggv[i][q] * hm[row][col];
          hm[row][col] = hd + zreg[i][q]*(th - hd);
        }
      }
  }

  asm volatile("s_waitcnt vmcnt(0)" ::: "memory");  // drain stray prefetches
  barrier_lds();
  for (int i = tid; i < 16*512; i += 512)
    h_st[(size_t)(r0 + (i>>9))*HH + (i&511)] = hm[i>>9][i&511];
}

// ---------------------------------------------------------------------------
// K4: head: eval BatchNorm + decoder GEMV + log_softmax.
//   d_out = [output (256x64) | h_bn (256x512)] fp32
// ---------------------------------------------------------------------------
__global__ __launch_bounds__(64) void head_kernel(
    const float* __restrict__ h_state, const float* __restrict__ decW,
    const float* __restrict__ decb, const float* __restrict__ bnw,
    const float* __restrict__ bnb, float* __restrict__ out)
{
  int b = blockIdx.x, o = threadIdx.x;
  __shared__ float hbn[HH];
  const float s = rsqrtf(1.f + 1e-5f);
  for (int j = o; j < HH; j += 64)
    hbn[j] = h_state[(long)b*HH + j] * (bnw[j] * s) + bnb[j];
  __syncthreads();
  float acc = decb[o];
  for (int j = 0; j < HH; ++j) acc += hbn[j] * decW[j*OO + o];
  float mx = acc;
#pragma unroll
  for (int off = 32; off > 0; off >>= 1) mx = fmaxf(mx, __shfl_xor(mx, off));
  float ex = __expf(acc - mx);
  float sum = ex;
#pragma unroll
  for (int off = 32; off > 0; off >>= 1) sum += __shfl_xor(sum, off);
  out[(long)b*OO + o] = acc - mx - __logf(sum);
  for (int j = o; j < HH; j += 64)
    out[(long)BB*OO + (long)b*HH + j] = hbn[j];
}

// ---------------------------------------------------------------------------
extern "C" void kernel_launch(void* const* d_in, const int* in_sizes, int n_in,
                              void* d_out, int out_size, void* d_ws, size_t ws_size,
                              hipStream_t stream) {
  const float* x     = (const float*)d_in[0];
  const float* delta = (const float*)d_in[1];
  const float* mm    = (const float*)d_in[2];
  const float* xf    = (const float*)d_in[3];
  const int*   bs    = (const int*)  d_in[4];
  const float* W_r   = (const float*)d_in[5];
  const float* U_r   = (const float*)d_in[6];
  const float* V_r   = (const float*)d_in[7];
  const float* b_r   = (const float*)d_in[8];
  const float* W_z   = (const float*)d_in[9];
  const float* U_z   = (const float*)d_in[10];
  const float* V_z   = (const float*)d_in[11];
  const float* b_z   = (const float*)d_in[12];
  const float* W     = (const float*)d_in[13];
  const float* U     = (const float*)d_in[14];
  const float* V     = (const float*)d_in[15];
  const float* b     = (const float*)d_in[16];
  const float* Wgx   = (const float*)d_in[17];
  const float* bgx   = (const float*)d_in[18];
  const float* Wgh   = (const float*)d_in[19];
  const float* bgh   = (const float*)d_in[20];
  const float* decW  = (const float*)d_in[21];
  const float* decb  = (const float*)d_in[22];
  const float* bnw   = (const float*)d_in[23];
  const float* bnb   = (const float*)d_in[24];

  auto rnd = [](size_t v) { return (v + 255) & ~(size_t)255; };
  const size_t fixed_bytes = rnd((size_t)2048*256*2) + rnd(2048*4)
                           + rnd((size_t)16*64*64*8*2) + rnd((size_t)16*32*64*8*2)
                           + rnd((size_t)BB*HH*4);
  int TC = 0;
  const int cands[5] = {128, 64, 32, 16, 8};
  for (int i = 0; i < 5; ++i) {
    size_t need = fixed_bytes + rnd((size_t)BB*cands[i]*KK*2) + rnd((size_t)BB*cands[i]*NN*2);
    if (need <= ws_size) { TC = cands[i]; break; }
  }
  if (TC == 0) return;

  char* p = (char*)d_ws;
  auto alloc = [&](size_t bytes) { char* r = p; p += (bytes + 255) & ~(size_t)255; return r; };
  unsigned short* A_chunk = (unsigned short*)alloc((size_t)BB * TC * KK * 2);
  unsigned short* PREc    = (unsigned short*)alloc((size_t)BB * TC * NN * 2);
  unsigned short* BwT     = (unsigned short*)alloc((size_t)2048 * 256 * 2);
  float*          bias    = (float*)alloc(2048 * 4);
  unsigned short* UzrP    = (unsigned short*)alloc((size_t)16*64*64*8 * 2);
  unsigned short* UhP     = (unsigned short*)alloc((size_t)16*32*64*8 * 2);
  float*          h_st    = (float*)alloc((size_t)BB * HH * 4);

  prep_kernel<<<5128, 256, 0, stream>>>(W_z, V_z, b_z, W_r, V_r, b_r, W, V, b,
                                        Wgh, bgh, U_z, U_r, U, BwT, bias, UzrP, UhP);
  const int nch = TT / TC;
  for (int c = 0; c < nch; ++c) {
    int t0 = c * TC;
    build_A_kernel<<<BB*TC/8, 256, 0, stream>>>(x, delta, mm, xf, Wgx, bgx, bs,
                                                A_chunk, t0, TC);
    gemm1_kernel<<<(BB*TC/128)*16, 256, 0, stream>>>(A_chunk, BwT, bias, bs,
                                                     PREc, t0, TC);
    scan_kernel<<<16, 512, 0, stream>>>(PREc, UzrP, UhP, bs, h_st, t0, TC);
  }
  head_kernel<<<256, 64, 0, stream>>>(h_st, decW, decb, bnw, bnb, (float*)d_out);
}

// Round 6
// 23013.167 us; speedup vs baseline: 1.7262x; 1.7262x over previous
//
#include <hip/hip_runtime.h>
#include <hip/hip_bf16.h>

typedef __attribute__((ext_vector_type(8))) short bf16x8;
typedef __attribute__((ext_vector_type(4))) float f32x4;
typedef __attribute__((ext_vector_type(4))) float fvec4;
typedef __attribute__((ext_vector_type(4))) unsigned short u16x4;
typedef __attribute__((ext_vector_type(4))) int i32x4;

#define DEVI __device__ __forceinline__

constexpr int BB = 256, TT = 1024, FF = 128, HH = 512, OO = 64;
constexpr int KK = 256;    // fused input width [x_imp | m]
constexpr int NN = 2048;   // fused gate width  [z | r | htilde | gamma_h]

DEVI unsigned short f2bf(float x) {
  unsigned int u = __float_as_uint(x);
  u += 0x7FFFu + ((u >> 16) & 1u);          // RNE
  return (unsigned short)(u >> 16);
}
DEVI float bf2f(unsigned short s) {
  return __uint_as_float(((unsigned int)s) << 16);
}

DEVI void gload16(const void* g, void* lds) {
  __builtin_amdgcn_global_load_lds(
      (const __attribute__((address_space(1))) void*)g,
      (__attribute__((address_space(3))) void*)lds, 16, 0, 0);
}

DEVI void barrier_lds() {       // raw barrier: waits LDS ops only, vmcnt SURVIVES
  asm volatile("s_waitcnt lgkmcnt(0)" ::: "memory");
  __builtin_amdgcn_s_barrier();
  __builtin_amdgcn_sched_barrier(0);
}

// slabHG address swizzle (shorts): involution within a row, applied on BOTH
// the stage source and every read/write.
DEVI int hgIdx(int row, int c) { return row*1024 + (c ^ ((row & 7) << 3)); }

// ---------------------------------------------------------------------------
// K0a: per-column scales s_n = max_k |U[k][n]|  (z:0..511, r:512..1023, h:1024..1535)
// ---------------------------------------------------------------------------
__global__ __launch_bounds__(256) void prep_scales_kernel(
    const float* __restrict__ U_z, const float* __restrict__ U_r,
    const float* __restrict__ Uh, float* __restrict__ uscale)
{
  int n = blockIdx.x * 256 + threadIdx.x;
  if (n >= 1536) return;
  const float* src = (n < 512) ? U_z : (n < 1024) ? U_r : Uh;
  int col = n & 511;
  float s = 0.f;
  for (int k = 0; k < HH; ++k) s = fmaxf(s, fabsf(src[k*HH + col]));
  uscale[n] = fmaxf(s, 1e-30f);
}

// ---------------------------------------------------------------------------
// K0b: pack weights.
//   BwT [2048][256] bf16 : row n = column n of fused K x N weight.
//   bias[2048] f32 : b_* + colsum(V_*)  (gamma rows: b_gamma_h)
//   UzrQ i8 [8 kt][64 nt][64 l][16 j] : nt<32 -> U_z cols, else U_r cols
//   UhQ  i8 [8 kt][32 nt][64 l][16 j] : U
//   value (kt,nt,l,j) = round(U[k][col]/s_col*127), k = kt*64+(l>>4)*16+j,
//   col = (nt&31)*16+(l&15).  A-side uses the identical (p=l>>4, j)->k map.
// ---------------------------------------------------------------------------
__global__ __launch_bounds__(256) void prep_kernel(
    const float* __restrict__ W_z, const float* __restrict__ V_z, const float* __restrict__ b_z,
    const float* __restrict__ W_r, const float* __restrict__ V_r, const float* __restrict__ b_r,
    const float* __restrict__ Wh,  const float* __restrict__ Vh,  const float* __restrict__ bh,
    const float* __restrict__ Wgh, const float* __restrict__ bgh,
    const float* __restrict__ U_z, const float* __restrict__ U_r, const float* __restrict__ Uh,
    const float* __restrict__ uscale,
    unsigned short* __restrict__ BwT, float* __restrict__ bias,
    int* __restrict__ UzrQ, int* __restrict__ UhQ)
{
  int idx = blockIdx.x * 256 + threadIdx.x;
  if (idx < 524288) {                       // BwT
    int n = idx >> 8, k = idx & 255;
    float v;
    if (n < 512)       { int h = n;        v = (k < 128) ? W_z[k*HH + h] : -V_z[(k-128)*HH + h]; }
    else if (n < 1024) { int h = n - 512;  v = (k < 128) ? W_r[k*HH + h] : -V_r[(k-128)*HH + h]; }
    else if (n < 1536) { int h = n - 1024; v = (k < 128) ? Wh [k*HH + h] : -Vh [(k-128)*HH + h]; }
    else               { int h = n - 1536; v = (k < 128) ? 0.f : Wgh[(k-128)*HH + h]; }
    BwT[n*256 + k] = f2bf(v);
    return;
  }
  idx -= 524288;
  if (idx < 2048) {                         // bias
    int n = idx; float v;
    if (n < 512)       { float s = b_z[n];      for (int f = 0; f < FF; ++f) s += V_z[f*HH + n];        v = s; }
    else if (n < 1024) { int h = n-512;  float s = b_r[h]; for (int f = 0; f < FF; ++f) s += V_r[f*HH + h]; v = s; }
    else if (n < 1536) { int h = n-1024; float s = bh[h];  for (int f = 0; f < FF; ++f) s += Vh[f*HH + h];  v = s; }
    else               { v = bgh[n-1536]; }
    bias[n] = v;
    return;
  }
  idx -= 2048;
  if (idx < 131072) {                       // UzrQ words
    int j0 = (idx & 3) * 4;
    int l  = (idx >> 2) & 63;
    int nt = (idx >> 8) & 63;
    int kt = idx >> 14;
    int col = (nt & 31)*16 + (l & 15);
    const float* src = (nt < 32) ? U_z : U_r;
    float sc = 127.f / uscale[(nt < 32 ? 0 : 512) + col];
    int word = 0;
#pragma unroll
    for (int b = 0; b < 4; ++b) {
      int k = kt*64 + (l >> 4)*16 + j0 + b;
      float q = fminf(fmaxf(rintf(src[k*HH + col] * sc), -127.f), 127.f);
      word |= ((int)q & 0xFF) << (8*b);
    }
    UzrQ[idx] = word;
    return;
  }
  idx -= 131072;
  if (idx < 65536) {                        // UhQ words
    int j0 = (idx & 3) * 4;
    int l  = (idx >> 2) & 63;
    int nt = (idx >> 8) & 31;
    int kt = idx >> 13;
    int col = nt*16 + (l & 15);
    float sc = 127.f / uscale[1024 + col];
    int word = 0;
#pragma unroll
    for (int b = 0; b < 4; ++b) {
      int k = kt*64 + (l >> 4)*16 + j0 + b;
      float q = fminf(fmaxf(rintf(Uh[k*HH + col] * sc), -127.f), 127.f);
      word |= ((int)q & 0xFF) << (8*b);
    }
    UhQ[idx] = word;
  }
}

// ---------------------------------------------------------------------------
// K1: imputation + fused A chunk [B*TC][256] bf16 = [x_imp | m]
// ---------------------------------------------------------------------------
__global__ __launch_bounds__(256) void build_A_kernel(
    const float* __restrict__ x, const float* __restrict__ delta,
    const float* __restrict__ mm, const float* __restrict__ xf,
    const float* __restrict__ Wgx, const float* __restrict__ bgx,
    const int* __restrict__ bs, unsigned short* __restrict__ A,
    int t0, int TC)
{
  int blk = blockIdx.x;
  int row8 = blk * 8;
  int b0  = row8 / TC;
  int tl0 = row8 % TC;
  if (b0 >= bs[t0 + tl0]) return;
  int tid = threadIdx.x;
  int rl = row8 + (tid >> 5);
  int tc = tl0 + (tid >> 5);
  long gi = ((long)b0*TT + t0 + tc) * 32 + (tid & 31);
  int f0 = (tid & 31) * 4;
  fvec4 xv = ((const fvec4*)x)[gi];
  fvec4 dv = ((const fvec4*)delta)[gi];
  fvec4 mv = ((const fvec4*)mm)[gi];
  fvec4 fv = ((const fvec4*)xf)[gi];
  unsigned short ox[4], om[4];
#pragma unroll
  for (int j = 0; j < 4; ++j) {
    float g  = __expf(-fmaxf(dv[j]*Wgx[f0+j] + bgx[f0+j], 0.f));
    float xr = g*fv[j] + (1.f - g)*0.001f;
    float xi = (mv[j] > 0.5f) ? xr : xv[j];
    ox[j] = f2bf(xi); om[j] = f2bf(mv[j]);
  }
  *(u16x4*)(A + (long)rl*KK + f0)       = (u16x4){ox[0], ox[1], ox[2], ox[3]};
  *(u16x4*)(A + (long)rl*KK + 128 + f0) = (u16x4){om[0], om[1], om[2], om[3]};
}

// ---------------------------------------------------------------------------
// K2: chunk GEMM  PRE[m][n] = A[m][:] @ Bw[:,n] + bias[n]  (bf16 MFMA, K=256)
// ---------------------------------------------------------------------------
__global__ __launch_bounds__(256) void gemm1_kernel(
    const unsigned short* __restrict__ A, const unsigned short* __restrict__ BwT,
    const float* __restrict__ bias, const int* __restrict__ bs,
    unsigned short* __restrict__ PRE, int t0, int TC)
{
  int blk = blockIdx.x;
  int nt = blk & 15;
  int mt = blk >> 4;
  {
    int m0 = mt * 128;
    int b_ = m0 / TC;
    int bcheck = (TC >= 128) ? bs[t0 + (m0 % TC)] : bs[t0];
    if (b_ >= bcheck) return;
  }
  int tid = threadIdx.x;
  int w = tid >> 6, l = tid & 63;
  int wm = w >> 1, wn = w & 1;
  int lr = l & 15, lg = l >> 4;
  int m_base = mt*128 + wm*64;
  int n_base = nt*128 + wn*64;
  const unsigned short* Aptr = A   + (long)(m_base + lr)*KK + lg*8;
  const unsigned short* Bptr = BwT + (long)(n_base + lr)*KK + lg*8;
  f32x4 acc[4][4];
#pragma unroll
  for (int i = 0; i < 4; ++i)
#pragma unroll
    for (int j = 0; j < 4; ++j) acc[i][j] = (f32x4){0.f, 0.f, 0.f, 0.f};

#pragma unroll
  for (int kt = 0; kt < 8; ++kt) {
    bf16x8 af[4], bfr[4];
#pragma unroll
    for (int i = 0; i < 4; ++i) af[i]  = *(const bf16x8*)(Aptr + (long)i*16*KK + kt*32);
#pragma unroll
    for (int i = 0; i < 4; ++i) bfr[i] = *(const bf16x8*)(Bptr + (long)i*16*KK + kt*32);
#pragma unroll
    for (int ms = 0; ms < 4; ++ms)
#pragma unroll
      for (int ns = 0; ns < 4; ++ns)
        acc[ms][ns] = __builtin_amdgcn_mfma_f32_16x16x32_bf16(af[ms], bfr[ns], acc[ms][ns], 0, 0, 0);
  }
#pragma unroll
  for (int ms = 0; ms < 4; ++ms) {
    int gm0 = m_base + ms*16 + lg*4;
#pragma unroll
    for (int ns = 0; ns < 4; ++ns) {
      int gn = n_base + ns*16 + lr;
      float bv = bias[gn];
      bool is_gamma = (gn >= 1536);
#pragma unroll
      for (int q = 0; q < 4; ++q) {
        float v = acc[ms][ns][q] + bv;
        if (is_gamma) v = __expf(-fmaxf(v, 0.f));
        PRE[(long)(gm0 + q)*NN + gn] = f2bf(v);
      }
    }
  }
}

// ---------------------------------------------------------------------------
// K3: sequential scan, 16 blocks x 512 threads (8 waves), i8 MFMA (K=64).
//   U streamed as i8 (768 KB/step, half of bf16) via per-wave depth-2
//   global_load_lds pipeline with counted vmcnt. hd/a2 quantized per step
//   with dynamic per-block scale s = max|h| (exact bound, no clipping).
//   preact = PRE(bf16) + acc_i32 * s_col * s / 127^2.
// ---------------------------------------------------------------------------
__global__ __launch_bounds__(512) void scan_kernel(
    const unsigned short* __restrict__ PRE,
    const signed char* __restrict__ UzrQ,
    const signed char* __restrict__ UhQ,
    const float* __restrict__ uscale,
    const int* __restrict__ bs,
    float* __restrict__ h_st,
    float* __restrict__ sbuf,
    int t0, int TC)
{
  __shared__ __align__(16) signed char Ubuf[8][2][4096];   // 64 KB per-wave dbuf
  __shared__ __align__(16) i32x4 hd_l[8*64];               // 8 KB hd / a2 frags
  __shared__ __align__(16) unsigned short slabHG[16*1024]; // 32 KB [row][htld|r : gamma]
  __shared__ float hm[16][524];                            // 33.5 KB h master
  __shared__ float wmax[8];

  const int tid = threadIdx.x;
  const int r0 = blockIdx.x * 16;
  if (t0 > 0 && bs[t0] <= r0) return;

  const int w = tid >> 6, l = tid & 63, lr = l & 15, lg = l >> 4;
  const size_t rowStr = (size_t)TC * NN;

  signed char* slot0 = &Ubuf[w][0][0];
  signed char* slot1 = &Ubuf[w][1][0];

  auto STAGEA = [&](int u) {   // phase-A unit: kt=u>>1, half=u&1 (0=z,1=r), tiles {4w..4w+3}
    const signed char* src = UzrQ + ((size_t)(((u>>1)*64 + (u&1)*32 + w*4)*64) + l)*16;
    signed char* dst = (u & 1) ? slot1 : slot0;
#pragma unroll
    for (int i = 0; i < 4; ++i) gload16(src + (size_t)i*1024, dst + i*1024);
  };
  auto STAGEB = [&](int u) {   // phase-B unit: kt=u, tiles {4w..4w+3}
    const signed char* src = UhQ + ((size_t)((u*32 + w*4)*64) + l)*16;
    signed char* dst = (u & 1) ? slot1 : slot0;
#pragma unroll
    for (int i = 0; i < 4; ++i) gload16(src + (size_t)i*1024, dst + i*1024);
  };
  auto STAGEHG = [&](const unsigned short* PREn) {  // htilde+gamma halves, swizzled source
#pragma unroll
    for (int j = 0; j < 4; ++j) {
      int idx = w*4 + j;
      int row = idx >> 1;
      int phys = (idx & 1)*512 + l*8;
      int logi = phys ^ ((row & 7) << 3);
      const unsigned short* src = PREn + (size_t)row*rowStr + 1024 + logi;
      gload16(src, &slabHG[idx*512]);
    }
  };

  // per-thread dequant constants (VGPR loads, consumed long before staging matters)
  float zdq[4], rdq[4], hdq[4];
#pragma unroll
  for (int i = 0; i < 4; ++i) {
    int c = (w*4 + i)*16 + lr;
    zdq[i] = uscale[c]        * (1.f/16129.f);
    rdq[i] = uscale[512 + c]  * (1.f/16129.f);
    hdq[i] = uscale[1024 + c] * (1.f/16129.f);
  }
  if (tid < 8) wmax[tid] = (t0 == 0) ? 1e-20f : sbuf[blockIdx.x];

  if (t0 == 0) {
    for (int i = tid; i < 16*512; i += 512) hm[i>>9][i&511] = 0.f;
  } else {
    for (int i = tid; i < 16*512; i += 512)
      hm[i>>9][i&511] = h_st[(size_t)(r0 + (i>>9))*HH + (i&511)];
  }
  __builtin_amdgcn_sched_barrier(0);

  // prologue staging: HG(step 0), A0, A1  (12 loads outstanding)
  STAGEHG(PRE + (size_t)r0*TC*NN);
  STAGEA(0); STAGEA(1);

  for (int tc = 0; tc < TC; ++tc) {
    const int bsv = bs[t0 + tc];
    if (bsv <= r0) break;                  // descending bs: done forever
    const int na = min(16, bsv - r0);
    const unsigned short* PREstep = PRE + ((size_t)r0*TC + tc)*NN;
    const unsigned short* PREnext = PREstep + NN;

    barrier_lds();                         // S1: prev hm + wmax writes visible
    asm volatile("s_waitcnt vmcnt(8)" ::: "memory");  // HG landed; A0,A1 fly
    __builtin_amdgcn_sched_barrier(0);

    // dynamic quant scale for hd (exact bound: |hd| <= max|h| = s)
    float s = wmax[0];
#pragma unroll
    for (int i = 1; i < 8; ++i) s = fmaxf(s, wmax[i]);
    const float qs = 127.f / s;

    // pz/pr clump: the only VGPR global loads in the loop
    unsigned short pzr[2][4][4];
#pragma unroll
    for (int i = 0; i < 4; ++i)
#pragma unroll
      for (int q = 0; q < 4; ++q) {
        int row = lg*4 + q, col = (w*4 + i)*16 + lr;
        const unsigned short* pb = PREstep + (size_t)row*rowStr + col;
        pzr[0][i][q] = pb[0];
        pzr[1][i][q] = pb[512];
      }
    __builtin_amdgcn_sched_barrier(0);

    // hd build (one pass: kt = w): quantize (act? gamma*h : h) to i8 frags
    {
      const int k0 = w*64 + lg*16;
      const bool act = lr < na;
      bf16x8 g0 = *(const bf16x8*)&slabHG[hgIdx(lr, 512 + k0)];
      bf16x8 g1 = *(const bf16x8*)&slabHG[hgIdx(lr, 512 + k0 + 8)];
      i32x4 qw;
#pragma unroll
      for (int d = 0; d < 4; ++d) {
        int word = 0;
#pragma unroll
        for (int b = 0; b < 4; ++b) {
          int j = d*4 + b;
          float h  = hm[lr][k0 + j];
          float gv = bf2f((unsigned short)(j < 8 ? g0[j] : g1[j-8]));
          float hd = act ? gv*h : h;
          float q  = fminf(fmaxf(rintf(hd*qs), -127.f), 127.f);
          word |= ((int)q & 0xFF) << (8*b);
        }
        qw[d] = word;
      }
      hd_l[w*64 + l] = qw;
    }

    // hoist htilde-preact + gamma for my output cells (before r overwrites)
    float phv[4][4], ggv[4][4];
#pragma unroll
    for (int i = 0; i < 4; ++i)
#pragma unroll
      for (int q = 0; q < 4; ++q) {
        int row = lg*4 + q, col = (w*4 + i)*16 + lr;
        phv[i][q] = bf2f(slabHG[hgIdx(row, col)]);
        ggv[i][q] = bf2f(slabHG[hgIdx(row, 512 + col)]);
      }
    barrier_lds();                         // S2: hd_l ready

    // ---- phase A: z|r, 16 units, depth-2 pipeline ----
    i32x4 acc[8];
#pragma unroll
    for (int i = 0; i < 8; ++i) acc[i] = (i32x4){0, 0, 0, 0};
    i32x4 af;
#pragma unroll
    for (int u = 0; u < 16; ++u) {
      asm volatile("s_waitcnt vmcnt(4)" ::: "memory");
      __builtin_amdgcn_sched_barrier(0);
      const signed char* buf = (u & 1) ? slot1 : slot0;
      if (!(u & 1)) af = hd_l[(u>>1)*64 + l];
#pragma unroll
      for (int i = 0; i < 4; ++i) {
        i32x4 bfr = ((const i32x4*)buf)[i*64 + l];
        acc[(u&1)*4 + i] = __builtin_amdgcn_mfma_i32_16x16x64_i8(af, bfr, acc[(u&1)*4 + i], 0, 0, 0);
      }
      __builtin_amdgcn_sched_barrier(0);
      if (u < 14)       STAGEA(u + 2);
      else if (u == 14) STAGEB(0);
      else              STAGEB(1);
    }

    // epilogue A: z -> regs; r -> slabHG (cols 0..511)
    float zreg[4][4];
#pragma unroll
    for (int i = 0; i < 4; ++i)
#pragma unroll
      for (int q = 0; q < 4; ++q) {
        int row = lg*4 + q, col = (w*4 + i)*16 + lr;
        float az = bf2f(pzr[0][i][q]) + (float)acc[i][q]   * zdq[i] * s;
        float ar = bf2f(pzr[1][i][q]) + (float)acc[4+i][q] * rdq[i] * s;
        zreg[i][q] = 1.f/(1.f + __expf(-az));
        slabHG[hgIdx(row, col)] = f2bf(1.f/(1.f + __expf(-ar)));
      }
    barrier_lds();                         // S3: r ready; phase-A hd_l reads done

    // a2 = hd*r quantized (same slot rewrite; |hd_q*r| <= 127)
    {
      const int k0 = w*64 + lg*16;
      bf16x8 r0v = *(const bf16x8*)&slabHG[hgIdx(lr, k0)];
      bf16x8 r1v = *(const bf16x8*)&slabHG[hgIdx(lr, k0 + 8)];
      i32x4 qw = hd_l[w*64 + l], nw;
#pragma unroll
      for (int d = 0; d < 4; ++d) {
        int word = qw[d], out = 0;
#pragma unroll
        for (int b = 0; b < 4; ++b) {
          int j = d*4 + b;
          int hq = (int)(signed char)((word >> (8*b)) & 0xFF);
          float rv = bf2f((unsigned short)(j < 8 ? r0v[j] : r1v[j-8]));
          float q = fminf(fmaxf(rintf((float)hq * rv), -127.f), 127.f);
          out |= ((int)q & 0xFF) << (8*b);
        }
        nw[d] = out;
      }
      hd_l[w*64 + l] = nw;
    }
    barrier_lds();                         // S4: a2 frags ready

    // ---- phase B: htilde, 8 units; tail stages HG(t+1), A0, A1 ----
    i32x4 accB[4];
#pragma unroll
    for (int i = 0; i < 4; ++i) accB[i] = (i32x4){0, 0, 0, 0};
#pragma unroll
    for (int u = 0; u < 8; ++u) {
      asm volatile("s_waitcnt vmcnt(4)" ::: "memory");
      __builtin_amdgcn_sched_barrier(0);
      const signed char* buf = (u & 1) ? slot1 : slot0;
      i32x4 af2 = hd_l[u*64 + l];
#pragma unroll
      for (int i = 0; i < 4; ++i) {
        i32x4 bfr = ((const i32x4*)buf)[i*64 + l];
        accB[i] = __builtin_amdgcn_mfma_i32_16x16x64_i8(af2, bfr, accB[i], 0, 0, 0);
      }
      __builtin_amdgcn_sched_barrier(0);
      if (u < 6)       STAGEB(u + 2);
      else if (u == 6) STAGEHG(PREnext);
      else             STAGEA(0);
    }
    STAGEA(1);

    // epilogue B: h update + block max|h| for next step's quant scale
    float mloc = 0.f;
#pragma unroll
    for (int i = 0; i < 4; ++i)
#pragma unroll
      for (int q = 0; q < 4; ++q) {
        int row = lg*4 + q, col = (w*4 + i)*16 + lr;
        float hval;
        if (row < na) {
          float ah = phv[i][q] + (float)accB[i][q] * hdq[i] * s;
          float e  = __expf(2.f*ah);
          float th = 1.f - 2.f/(e + 1.f);          // tanh, overflow-safe
          float hd = ggv[i][q] * hm[row][col];
          hval = hd + zreg[i][q]*(th - hd);
          hm[row][col] = hval;
        } else {
          hval = hm[row][col];
        }
        mloc = fmaxf(mloc, fabsf(hval));
      }
#pragma unroll
    for (int off = 32; off > 0; off >>= 1) mloc = fmaxf(mloc, __shfl_xor(mloc, off));
    if (l == 0) wmax[w] = fmaxf(mloc, 1e-20f);
  }

  asm volatile("s_waitcnt vmcnt(0)" ::: "memory");  // drain stray prefetches
  barrier_lds();
  for (int i = tid; i < 16*512; i += 512)
    h_st[(size_t)(r0 + (i>>9))*HH + (i&511)] = hm[i>>9][i&511];
  if (tid == 0) {
    float s = wmax[0];
#pragma unroll
    for (int i = 1; i < 8; ++i) s = fmaxf(s, wmax[i]);
    sbuf[blockIdx.x] = s;
  }
}

// ---------------------------------------------------------------------------
// K4: head: eval BatchNorm + decoder GEMV + log_softmax.
//   d_out = [output (256x64) | h_bn (256x512)] fp32
// ---------------------------------------------------------------------------
__global__ __launch_bounds__(64) void head_kernel(
    const float* __restrict__ h_state, const float* __restrict__ decW,
    const float* __restrict__ decb, const float* __restrict__ bnw,
    const float* __restrict__ bnb, float* __restrict__ out)
{
  int b = blockIdx.x, o = threadIdx.x;
  __shared__ float hbn[HH];
  const float s = rsqrtf(1.f + 1e-5f);
  for (int j = o; j < HH; j += 64)
    hbn[j] = h_state[(long)b*HH + j] * (bnw[j] * s) + bnb[j];
  __syncthreads();
  float acc = decb[o];
  for (int j = 0; j < HH; ++j) acc += hbn[j] * decW[j*OO + o];
  float mx = acc;
#pragma unroll
  for (int off = 32; off > 0; off >>= 1) mx = fmaxf(mx, __shfl_xor(mx, off));
  float ex = __expf(acc - mx);
  float sum = ex;
#pragma unroll
  for (int off = 32; off > 0; off >>= 1) sum += __shfl_xor(sum, off);
  out[(long)b*OO + o] = acc - mx - __logf(sum);
  for (int j = o; j < HH; j += 64)
    out[(long)BB*OO + (long)b*HH + j] = hbn[j];
}

// ---------------------------------------------------------------------------
extern "C" void kernel_launch(void* const* d_in, const int* in_sizes, int n_in,
                              void* d_out, int out_size, void* d_ws, size_t ws_size,
                              hipStream_t stream) {
  const float* x     = (const float*)d_in[0];
  const float* delta = (const float*)d_in[1];
  const float* mm    = (const float*)d_in[2];
  const float* xf    = (const float*)d_in[3];
  const int*   bs    = (const int*)  d_in[4];
  const float* W_r   = (const float*)d_in[5];
  const float* U_r   = (const float*)d_in[6];
  const float* V_r   = (const float*)d_in[7];
  const float* b_r   = (const float*)d_in[8];
  const float* W_z   = (const float*)d_in[9];
  const float* U_z   = (const float*)d_in[10];
  const float* V_z   = (const float*)d_in[11];
  const float* b_z   = (const float*)d_in[12];
  const float* W     = (const float*)d_in[13];
  const float* U     = (const float*)d_in[14];
  const float* V     = (const float*)d_in[15];
  const float* b     = (const float*)d_in[16];
  const float* Wgx   = (const float*)d_in[17];
  const float* bgx   = (const float*)d_in[18];
  const float* Wgh   = (const float*)d_in[19];
  const float* bgh   = (const float*)d_in[20];
  const float* decW  = (const float*)d_in[21];
  const float* decb  = (const float*)d_in[22];
  const float* bnw   = (const float*)d_in[23];
  const float* bnb   = (const float*)d_in[24];

  auto rnd = [](size_t v) { return (v + 255) & ~(size_t)255; };
  const size_t fixed_bytes = rnd((size_t)2048*256*2) + rnd(2048*4)
                           + rnd((size_t)512*1024) + rnd((size_t)256*1024)
                           + rnd(1536*4) + rnd(64)
                           + rnd((size_t)BB*HH*4);
  int TC = 0;
  const int cands[5] = {128, 64, 32, 16, 8};
  for (int i = 0; i < 5; ++i) {
    size_t need = fixed_bytes + rnd((size_t)BB*cands[i]*KK*2) + rnd((size_t)BB*cands[i]*NN*2);
    if (need <= ws_size) { TC = cands[i]; break; }
  }
  if (TC == 0) return;

  char* p = (char*)d_ws;
  auto alloc = [&](size_t bytes) { char* r = p; p += (bytes + 255) & ~(size_t)255; return r; };
  unsigned short* A_chunk = (unsigned short*)alloc((size_t)BB * TC * KK * 2);
  unsigned short* PREc    = (unsigned short*)alloc((size_t)BB * TC * NN * 2);
  unsigned short* BwT     = (unsigned short*)alloc((size_t)2048 * 256 * 2);
  float*          bias    = (float*)alloc(2048 * 4);
  int*            UzrQ    = (int*)alloc((size_t)512 * 1024);
  int*            UhQ     = (int*)alloc((size_t)256 * 1024);
  float*          uscale  = (float*)alloc(1536 * 4);
  float*          sbuf    = (float*)alloc(64);
  float*          h_st    = (float*)alloc((size_t)BB * HH * 4);

  prep_scales_kernel<<<6, 256, 0, stream>>>(U_z, U_r, U, uscale);
  prep_kernel<<<2824, 256, 0, stream>>>(W_z, V_z, b_z, W_r, V_r, b_r, W, V, b,
                                        Wgh, bgh, U_z, U_r, U, uscale,
                                        BwT, bias, UzrQ, UhQ);
  const int nch = TT / TC;
  for (int c = 0; c < nch; ++c) {
    int t0 = c * TC;
    build_A_kernel<<<BB*TC/8, 256, 0, stream>>>(x, delta, mm, xf, Wgx, bgx, bs,
                                                A_chunk, t0, TC);
    gemm1_kernel<<<(BB*TC/128)*16, 256, 0, stream>>>(A_chunk, BwT, bias, bs,
                                                     PREc, t0, TC);
    scan_kernel<<<16, 512, 0, stream>>>(PREc, (const signed char*)UzrQ,
                                        (const signed char*)UhQ, uscale, bs,
                                        h_st, sbuf, t0, TC);
  }
  head_kernel<<<256, 64, 0, stream>>>(h_st, decW, decb, bnw, bnb, (float*)d_out);
}